// Round 2
// baseline (4242.186 us; speedup 1.0000x reference)
//
#include <hip/hip_runtime.h>

// ---------------------------------------------------------------------------
// E2E seq2seq: encoder (Linear+ReLU) -> 64-step attention-GRU decoder ->
// logits GEMM [4096x128]x[128x32000] + log_softmax.
//
// Structure:
//   K1  transpose weights (coalesced GEMV layouts), convert Wout -> fp16
//   K2  encoder: enc_out [S,B,E], uh [S,B,A]  (f32, ws)
//   K3  decode: 64 WGs (one per batch lane), 1024 threads (16 waves = 4/SIMD
//       for latency hiding), T=64 sequential steps. enc_out/uh pinned in LDS.
//       __launch_bounds__(1024, 4): 1 WG/CU is the LDS-limited reality, so
//       give the allocator the full 128-VGPR budget (64-VGPR cap => spills
//       => scratch traffic evicted weights from L2 => 1.5 GB HBM fetch).
//   K4  logits pass1 (MFMA fp16): per-row-block online-softmax partials
//   K5  reduce partials -> L[row] = max + log(sumexp)
//   K6  logits pass2 (MFMA fp16): recompute tile, write x - L[row] (524 MB)
// ---------------------------------------------------------------------------

typedef _Float16 half8 __attribute__((ext_vector_type(8)));
typedef float floatx4 __attribute__((ext_vector_type(4)));

__device__ __forceinline__ float fast_tanh(float x) {
  float e = __expf(2.0f * x);
  return 1.0f - 2.0f / (e + 1.0f);   // saturates correctly when e -> inf / 0
}
__device__ __forceinline__ float fast_sigmoid(float x) {
  return 1.0f / (1.0f + __expf(-x));
}

// ---------------- prep kernels ----------------
__global__ void transpose_kernel(const float* __restrict__ src,
                                 float* __restrict__ dst, int R, int C) {
  int i = blockIdx.x * 256 + threadIdx.x;
  if (i < R * C) {
    int r = i / C, c = i - r * C;
    dst[c * R + r] = src[i];
  }
}

__global__ void cvt_f16_kernel(const float* __restrict__ src,
                               _Float16* __restrict__ dst, int n) {
  int i = blockIdx.x * 256 + threadIdx.x;
  if (i < n) dst[i] = (_Float16)src[i];
}

// ---------------- encoder ----------------
// grid 8192 (= s*64+b), 128 threads. eo_ws/uh_ws layout: [(s*64+b)][128]
__global__ __launch_bounds__(128) void encoder_kernel(
    const float* __restrict__ emb, const float* __restrict__ WeT,
    const float* __restrict__ b_enc, const float* __restrict__ UwT,
    const float* __restrict__ U_b, const int* __restrict__ batch_x,
    float* __restrict__ eo_ws, float* __restrict__ uh_ws) {
  __shared__ float x[128];
  __shared__ float row[128];
  int idx = blockIdx.x;
  int tid = threadIdx.x;
  int id = batch_x[idx];
  x[tid] = emb[id * 128 + tid];
  __syncthreads();
  float acc = b_enc[tid];
#pragma unroll 4
  for (int d = 0; d < 128; ++d) acc += WeT[d * 128 + tid] * x[d];
  acc = fmaxf(acc, 0.0f);
  row[tid] = acc;
  eo_ws[idx * 128 + tid] = acc;
  __syncthreads();
  float a2 = U_b[tid];
#pragma unroll 4
  for (int e = 0; e < 128; ++e) a2 += UwT[e * 128 + tid] * row[e];
  uh_ws[idx * 128 + tid] = a2;
}

// ---------------- decoder ----------------
// 64 WGs (one per batch lane b), 1024 threads (16 waves), dyn LDS 149008 B.
// Per step (10 barriers):
//   A    : gh partials (768 thr, Ksplit2) + wq partials (256 thr, Ksplit2)
//   A-red: wq (128) | gh (384) | issue emb prefetch for t+1 (128)
//   B    : scores partials, 8-way A-split, 16 tanh/thread
//   B-red: wave0 reduces 8 partials + softmax (butterfly)
//   C    : ctx partials, 8-way s-split
//   C-red: ctx scale
//   D    : rnn partials, 8-way K-split over [py|ctx]
//   D-red: rnn (128) | write prefetched py_next (128)
//   E    : gi partials (768 thr, Ksplit2)
//   F    : gate fusion (gi reduce folded in) + h update + Hf store
__global__ __launch_bounds__(1024, 4) void decode_kernel(
    const float* __restrict__ emb, const float* __restrict__ WwT,
    const float* __restrict__ Wb, const float* __restrict__ vw,
    const float* __restrict__ vb, const float* __restrict__ WcT,
    const float* __restrict__ Wcb, const float* __restrict__ WihT,
    const float* __restrict__ bih, const float* __restrict__ WhhT,
    const float* __restrict__ bhh, const int* __restrict__ batch_y,
    const float* __restrict__ eo_ws, const float* __restrict__ uh_ws,
    _Float16* __restrict__ Hf) {
  extern __shared__ float sm[];
  float* eo  = sm;                 // 128*129 (pad stride 129: conflict-free)
  float* uhs = eo + 128 * 129;     // 128*129
  float* h   = uhs + 128 * 129;    // 128
  float* wq  = h + 128;            // 128
  float* sc  = wq + 128;           // 128
  float* ctx = sc + 128;           // 128
  float* py0 = ctx + 128;          // 128
  float* py1 = py0 + 128;          // 128
  float* rnn = py1 + 128;          // 128
  float* gh  = rnn + 128;          // 384 (reduced gh, incl bhh)
  float* gP  = gh + 384;           // 2*384 partials (gh in A, gi in E)
  float* red = gP + 768;           // 8*128 partials
  float* vws = red + 1024;         // 128 (v_w staged)
  float* bb  = vws + 128;          // 1024: Wb[128] bhh[384] Wcb[128] bih[384]
  float* scal = bb + 1024;         // [0]=1/softmax_sum, [1]=v_b

  const int tid = threadIdx.x;
  const int b = blockIdx.x;

  // ---- init: stage eo/uh tiles, v, biases ----
  for (int i = tid; i < 128 * 128; i += 1024) {
    int s = i >> 7, e = i & 127;
    eo[s * 129 + e]  = eo_ws[(s * 64 + b) * 128 + e];
    uhs[s * 129 + e] = uh_ws[(s * 64 + b) * 128 + e];
  }
  if (tid < 128) vws[tid] = vw[tid];
  if (tid < 128) bb[tid] = Wb[tid];
  else if (tid < 512) bb[tid] = bhh[tid - 128];
  else if (tid < 640) bb[tid] = Wcb[tid - 512];
  else bb[tid] = bih[tid - 640];
  if (tid == 0) scal[1] = vb[0];
  __syncthreads();
  // h0 = sum_s enc_out  (8-way split)
  {
    int e = tid & 127, sub = tid >> 7;
    float a0 = 0.f;
    for (int s = sub * 16; s < sub * 16 + 16; ++s) a0 += eo[s * 129 + e];
    red[sub * 128 + e] = a0;
  }
  __syncthreads();
  if (tid < 128) {
    float a = 0.f;
#pragma unroll
    for (int k = 0; k < 8; ++k) a += red[k * 128 + tid];
    h[tid] = a;
    py0[tid] = emb[(50000 - 1) * 128 + tid];   // BOS embedding
  }
  __syncthreads();

  float* pyCur = py0;
  float* pyNext = py1;
  float vPy = 0.f;

  for (int t = 0; t < 64; ++t) {
    // ---- phase A: gh partials + wq partials (both read only h) ----
    if (tid < 768) {
      int part = (tid >= 384) ? 1 : 0;
      int g = tid - (part ? 384 : 0);
      const float* W = WhhT + (part ? 64 * 384 : 0) + g;
      const float* hh = h + (part ? 64 : 0);
      float a0 = 0.f, a1 = 0.f, a2 = 0.f, a3 = 0.f;
      for (int j = 0; j < 64; j += 4) {
        a0 += W[(j + 0) * 384] * hh[j + 0];
        a1 += W[(j + 1) * 384] * hh[j + 1];
        a2 += W[(j + 2) * 384] * hh[j + 2];
        a3 += W[(j + 3) * 384] * hh[j + 3];
      }
      gP[part * 384 + g] = (a0 + a1) + (a2 + a3);
    } else {
      int t2 = tid - 768;
      int part = t2 >> 7, a = t2 & 127;
      const float* W = WwT + (part ? 64 * 128 : 0) + a;
      const float* hh = h + (part ? 64 : 0);
      float a0 = 0.f, a1 = 0.f, a2 = 0.f, a3 = 0.f;
      for (int e = 0; e < 64; e += 4) {
        a0 += W[(e + 0) * 128] * hh[e + 0];
        a1 += W[(e + 1) * 128] * hh[e + 1];
        a2 += W[(e + 2) * 128] * hh[e + 2];
        a3 += W[(e + 3) * 128] * hh[e + 3];
      }
      red[part * 128 + a] = (a0 + a1) + (a2 + a3);
    }
    __syncthreads();
    // ---- A-reduce + prefetch issue ----
    if (tid < 128) {
      wq[tid] = red[tid] + red[128 + tid] + bb[tid];
    } else if (tid < 512) {
      int g = tid - 128;
      gh[g] = gP[g] + gP[384 + g] + bb[128 + g];
    } else if (tid < 640) {
      if (t < 63) {   // issue next step's prev_y embedding row load
        int pid = batch_y[t * 64 + b];
        vPy = emb[pid * 128 + (tid - 512)];
      }
    }
    __syncthreads();
    // ---- phase B: scores partials. s=tid&127, 16 tanh each ----
    {
      int s = tid & 127, sub = tid >> 7;
      const float* ur = uhs + s * 129 + sub * 16;
      const float* wr = wq + sub * 16;
      const float* vr = vws + sub * 16;
      float acc = 0.f;
#pragma unroll
      for (int a = 0; a < 16; ++a) acc += vr[a] * fast_tanh(wr[a] + ur[a]);
      red[sub * 128 + s] = acc;
    }
    __syncthreads();
    // ---- B-reduce + softmax (wave 0) ----
    if (tid < 64) {
      float s0 = scal[1], s1 = scal[1];
#pragma unroll
      for (int k = 0; k < 8; ++k) {
        s0 += red[k * 128 + tid];
        s1 += red[k * 128 + tid + 64];
      }
      float m = fmaxf(s0, s1);
      for (int o = 32; o >= 1; o >>= 1) m = fmaxf(m, __shfl_xor(m, o, 64));
      float e0_ = __expf(s0 - m);
      float e1_ = __expf(s1 - m);
      sc[tid] = e0_; sc[tid + 64] = e1_;
      float ss = e0_ + e1_;
      for (int o = 32; o >= 1; o >>= 1) ss += __shfl_xor(ss, o, 64);
      if (tid == 0) scal[0] = 1.0f / ss;
    }
    __syncthreads();
    // ---- phase C: ctx partials, 8-way s-split ----
    {
      int e = tid & 127, sub = tid >> 7;
      float a0 = 0.f, a1 = 0.f;
      for (int s = sub * 16; s < sub * 16 + 16; s += 2) {
        a0 += sc[s] * eo[s * 129 + e];
        a1 += sc[s + 1] * eo[(s + 1) * 129 + e];
      }
      red[sub * 128 + e] = a0 + a1;
    }
    __syncthreads();
    if (tid < 128) {
      float a = 0.f;
#pragma unroll
      for (int k = 0; k < 8; ++k) a += red[k * 128 + tid];
      ctx[tid] = a * scal[0];
    }
    __syncthreads();
    // ---- phase D: rnn partials, 8-way K-split over [py|ctx] ----
    {
      int j = tid & 127, sub = tid >> 7;
      const float* src = (sub < 4) ? (pyCur + sub * 32) : (ctx + (sub - 4) * 32);
      const float* W = WcT + (sub * 32) * 128 + j;
      float a0 = 0.f, a1 = 0.f, a2 = 0.f, a3 = 0.f;
      for (int i2 = 0; i2 < 32; i2 += 4) {
        a0 += W[(i2 + 0) * 128] * src[i2 + 0];
        a1 += W[(i2 + 1) * 128] * src[i2 + 1];
        a2 += W[(i2 + 2) * 128] * src[i2 + 2];
        a3 += W[(i2 + 3) * 128] * src[i2 + 3];
      }
      red[sub * 128 + j] = (a0 + a1) + (a2 + a3);
    }
    __syncthreads();
    // ---- D-reduce + prefetch write ----
    if (tid < 128) {
      float a = 0.f;
#pragma unroll
      for (int k = 0; k < 8; ++k) a += red[k * 128 + tid];
      rnn[tid] = a + bb[512 + tid];
    } else if (tid >= 512 && tid < 640) {
      if (t < 63) pyNext[tid - 512] = vPy;
    }
    __syncthreads();
    // ---- phase E: gi partials (768 thr, Ksplit2) ----
    if (tid < 768) {
      int part = (tid >= 384) ? 1 : 0;
      int g = tid - (part ? 384 : 0);
      const float* W = WihT + (part ? 64 * 384 : 0) + g;
      const float* rr = rnn + (part ? 64 : 0);
      float a0 = 0.f, a1 = 0.f, a2 = 0.f, a3 = 0.f;
      for (int j = 0; j < 64; j += 4) {
        a0 += W[(j + 0) * 384] * rr[j + 0];
        a1 += W[(j + 1) * 384] * rr[j + 1];
        a2 += W[(j + 2) * 384] * rr[j + 2];
        a3 += W[(j + 3) * 384] * rr[j + 3];
      }
      gP[part * 384 + g] = (a0 + a1) + (a2 + a3);
    }
    __syncthreads();
    // ---- phase F: gate fusion (gi reduce folded in) + h update ----
    if (tid < 128) {
      float ir = gP[tid] + gP[384 + tid] + bb[640 + tid];
      float iz = gP[128 + tid] + gP[384 + 128 + tid] + bb[640 + 128 + tid];
      float in_ = gP[256 + tid] + gP[384 + 256 + tid] + bb[640 + 256 + tid];
      float r = fast_sigmoid(ir + gh[tid]);
      float z = fast_sigmoid(iz + gh[128 + tid]);
      float ng = fast_tanh(in_ + r * gh[256 + tid]);
      float hn = (1.f - z) * ng + z * h[tid];
      h[tid] = hn;
      Hf[(t * 64 + b) * 128 + tid] = (_Float16)hn;
    }
    __syncthreads();
    float* tmp = pyCur; pyCur = pyNext; pyNext = tmp;
  }
}

// ---------------- logits GEMM (fp16 MFMA) ----------------
// grid (250, 32), 256 threads; 128x128 C-tile per WG; K=128.
// LDS: A-tile + B-tile, fp16, row stride 136 (2-way conflicts only).
// PASS 1: per-row (max, sumexp) partials over this 128-col block.
// PASS 2: out[row][col] = x - L[row].
template <int PASS>
__global__ __launch_bounds__(256) void logits_kernel(
    const _Float16* __restrict__ Ah,   // [4096][128]
    const _Float16* __restrict__ Bh,   // [32000][128] (Wout rows, K-major)
    const float* __restrict__ bout, const float* __restrict__ Lrow,
    float* __restrict__ pmax, float* __restrict__ psum,
    float* __restrict__ out) {
  extern __shared__ char smem_raw[];
  _Float16* At = (_Float16*)smem_raw;                 // 128*136
  _Float16* Bt = (_Float16*)(smem_raw + 128 * 136 * 2);

  const int nb = blockIdx.x;   // 0..249
  const int mb = blockIdx.y;   // 0..31
  const int tid = threadIdx.x;
  const int lane = tid & 63;
  const int wid = tid >> 6;
  const int m0 = mb * 128, n0 = nb * 128;

  const uint4* Ag = (const uint4*)(Ah + (size_t)m0 * 128);
  const uint4* Bg = (const uint4*)(Bh + (size_t)n0 * 128);
  for (int i = tid; i < 2048; i += 256) {
    int r = i >> 4, c = i & 15;
    *(uint4*)(At + r * 136 + c * 8) = Ag[r * 16 + c];
    *(uint4*)(Bt + r * 136 + c * 8) = Bg[r * 16 + c];
  }
  __syncthreads();

  const int wm = wid >> 1, wn = wid & 1;
  const int lr = lane & 15;
  const int quad = lane >> 4;

  floatx4 acc[4][4];
  const floatx4 z4 = {0.f, 0.f, 0.f, 0.f};
  for (int i = 0; i < 4; ++i)
    for (int j = 0; j < 4; ++j) acc[i][j] = z4;

  for (int kk = 0; kk < 4; ++kk) {
    int kof = kk * 32 + quad * 8;
    half8 af[4], bfr[4];
#pragma unroll
    for (int ms = 0; ms < 4; ++ms)
      af[ms] = *(const half8*)(At + (wm * 64 + ms * 16 + lr) * 136 + kof);
#pragma unroll
    for (int ns = 0; ns < 4; ++ns)
      bfr[ns] = *(const half8*)(Bt + (wn * 64 + ns * 16 + lr) * 136 + kof);
#pragma unroll
    for (int ms = 0; ms < 4; ++ms)
#pragma unroll
      for (int ns = 0; ns < 4; ++ns)
        acc[ms][ns] = __builtin_amdgcn_mfma_f32_16x16x32_f16(
            af[ms], bfr[ns], acc[ms][ns], 0, 0, 0);
  }

  float bcol[4];
#pragma unroll
  for (int ns = 0; ns < 4; ++ns)
    bcol[ns] = bout[n0 + wn * 64 + ns * 16 + lr];

  if (PASS == 1) {
    __syncthreads();   // done with tiles; reuse LDS for reductions
    float* red_m = (float*)smem_raw;   // [2][128]
    float* red_s = red_m + 256;        // [2][128]
#pragma unroll
    for (int ms = 0; ms < 4; ++ms) {
#pragma unroll
      for (int r = 0; r < 4; ++r) {
        float v0 = acc[ms][0][r] + bcol[0];
        float v1 = acc[ms][1][r] + bcol[1];
        float v2 = acc[ms][2][r] + bcol[2];
        float v3 = acc[ms][3][r] + bcol[3];
        float vmax = fmaxf(fmaxf(v0, v1), fmaxf(v2, v3));
        for (int o = 1; o < 16; o <<= 1)
          vmax = fmaxf(vmax, __shfl_xor(vmax, o, 16));
        float s = __expf(v0 - vmax) + __expf(v1 - vmax) +
                  __expf(v2 - vmax) + __expf(v3 - vmax);
        for (int o = 1; o < 16; o <<= 1) s += __shfl_xor(s, o, 16);
        if (lr == 0) {
          int row = wm * 64 + ms * 16 + quad * 4 + r;
          red_m[wn * 128 + row] = vmax;
          red_s[wn * 128 + row] = s;
        }
      }
    }
    __syncthreads();
    if (tid < 128) {
      float ma = red_m[tid], mb2 = red_m[128 + tid];
      float M = fmaxf(ma, mb2);
      float S = red_s[tid] * __expf(ma - M) + red_s[128 + tid] * __expf(mb2 - M);
      pmax[(size_t)(m0 + tid) * 250 + nb] = M;
      psum[(size_t)(m0 + tid) * 250 + nb] = S;
    }
  } else {
#pragma unroll
    for (int ms = 0; ms < 4; ++ms) {
#pragma unroll
      for (int r = 0; r < 4; ++r) {
        int grow = m0 + wm * 64 + ms * 16 + quad * 4 + r;
        float L = Lrow[grow];
        float* orow = out + (size_t)grow * 32000 + n0 + wn * 64 + lr;
#pragma unroll
        for (int ns = 0; ns < 4; ++ns)
          orow[ns * 16] = acc[ms][ns][r] + bcol[ns] - L;
      }
    }
  }
}

__global__ void reduce_l_kernel(const float* __restrict__ pmax,
                                const float* __restrict__ psum,
                                float* __restrict__ Lrow) {
  int row = blockIdx.x * 256 + threadIdx.x;
  if (row >= 4096) return;
  const float* pm = pmax + (size_t)row * 250;
  const float* ps = psum + (size_t)row * 250;
  float M = -1e30f;
  for (int i = 0; i < 250; ++i) M = fmaxf(M, pm[i]);
  float S = 0.f;
  for (int i = 0; i < 250; ++i) S += ps[i] * __expf(pm[i] - M);
  Lrow[row] = M + logf(S);
}

// ---------------------------------------------------------------------------
extern "C" void kernel_launch(void* const* d_in, const int* in_sizes, int n_in,
                              void* d_out, int out_size, void* d_ws,
                              size_t ws_size, hipStream_t stream) {
  const float* emb   = (const float*)d_in[0];
  const float* W_enc = (const float*)d_in[1];
  const float* b_enc = (const float*)d_in[2];
  const float* U_w   = (const float*)d_in[3];
  const float* U_b   = (const float*)d_in[4];
  const float* Ww    = (const float*)d_in[5];
  const float* Wb    = (const float*)d_in[6];
  const float* v_w   = (const float*)d_in[7];
  const float* v_b   = (const float*)d_in[8];
  const float* Wc_w  = (const float*)d_in[9];
  const float* Wc_b  = (const float*)d_in[10];
  const float* Wih   = (const float*)d_in[11];
  const float* bih   = (const float*)d_in[12];
  const float* Whh   = (const float*)d_in[13];
  const float* bhh   = (const float*)d_in[14];
  const float* Wout  = (const float*)d_in[15];
  const float* bout  = (const float*)d_in[16];
  const int* batch_x = (const int*)d_in[17];
  const int* batch_y = (const int*)d_in[18];
  float* out = (float*)d_out;

  char* w = (char*)d_ws;
  size_t off = 0;
  auto alloc = [&](size_t bytes) {
    void* p = w + off;
    off += (bytes + 255) & ~(size_t)255;
    return p;
  };
  float* eo_ws = (float*)alloc(128 * 64 * 128 * 4);
  float* uh_ws = (float*)alloc(128 * 64 * 128 * 4);
  float* WeT   = (float*)alloc(128 * 128 * 4);
  float* UwT   = (float*)alloc(128 * 128 * 4);
  float* WwT   = (float*)alloc(128 * 128 * 4);
  float* WcT   = (float*)alloc(256 * 128 * 4);
  float* WihT  = (float*)alloc(128 * 384 * 4);
  float* WhhT  = (float*)alloc(128 * 384 * 4);
  _Float16* Hf  = (_Float16*)alloc(4096 * 128 * 2);
  _Float16* WoH = (_Float16*)alloc((size_t)32000 * 128 * 2);
  float* pmax = (float*)alloc((size_t)4096 * 250 * 4);
  float* psum = (float*)alloc((size_t)4096 * 250 * 4);
  float* Lrow = (float*)alloc(4096 * 4);
  (void)ws_size; (void)in_sizes; (void)n_in; (void)out_size;

  // opt-in >64KB dynamic LDS (idempotent; not a stream op)
  // decode LDS: 2*128*129 + 9*128 + 384 + 768 + 1024 + 1024 + 4 floats
  const int DEC_SH = (2 * 128 * 129 + 9 * 128 + 384 + 768 + 1024 + 1024 + 4) * 4;
  const int P3_SH = 2 * 128 * 136 * 2;                                  // 69632
  hipFuncSetAttribute((const void*)decode_kernel,
                      hipFuncAttributeMaxDynamicSharedMemorySize, DEC_SH);
  hipFuncSetAttribute((const void*)(logits_kernel<1>),
                      hipFuncAttributeMaxDynamicSharedMemorySize, P3_SH);
  hipFuncSetAttribute((const void*)(logits_kernel<2>),
                      hipFuncAttributeMaxDynamicSharedMemorySize, P3_SH);

  // prep: transposes + fp16 convert
  transpose_kernel<<<(128 * 128 + 255) / 256, 256, 0, stream>>>(W_enc, WeT, 128, 128);
  transpose_kernel<<<(128 * 128 + 255) / 256, 256, 0, stream>>>(U_w, UwT, 128, 128);
  transpose_kernel<<<(128 * 128 + 255) / 256, 256, 0, stream>>>(Ww, WwT, 128, 128);
  transpose_kernel<<<(128 * 256 + 255) / 256, 256, 0, stream>>>(Wc_w, WcT, 128, 256);
  transpose_kernel<<<(384 * 128 + 255) / 256, 256, 0, stream>>>(Wih, WihT, 384, 128);
  transpose_kernel<<<(384 * 128 + 255) / 256, 256, 0, stream>>>(Whh, WhhT, 384, 128);
  cvt_f16_kernel<<<(32000 * 128 + 255) / 256, 256, 0, stream>>>(Wout, WoH, 32000 * 128);

  encoder_kernel<<<128 * 64, 128, 0, stream>>>(emb, WeT, b_enc, UwT, U_b,
                                               batch_x, eo_ws, uh_ws);

  decode_kernel<<<64, 1024, DEC_SH, stream>>>(emb, WwT, Wb, v_w, v_b, WcT, Wc_b,
                                              WihT, bih, WhhT, bhh, batch_y,
                                              eo_ws, uh_ws, Hf);

  dim3 g3(250, 32);
  logits_kernel<1><<<g3, 256, P3_SH, stream>>>(Hf, WoH, bout, nullptr, pmax,
                                               psum, nullptr);
  reduce_l_kernel<<<16, 256, 0, stream>>>(pmax, psum, Lrow);
  logits_kernel<2><<<g3, 256, P3_SH, stream>>>(Hf, WoH, bout, Lrow, nullptr,
                                               nullptr, out);
}

// Round 4
// 1699.615 us; speedup vs baseline: 2.4960x; 2.4960x over previous
//
#include <hip/hip_runtime.h>

// ---------------------------------------------------------------------------
// E2E seq2seq: encoder (Linear+ReLU) -> 64-step attention-GRU decoder ->
// logits GEMM [4096x128]x[128x32000] + log_softmax.
//
// Structure:
//   K1  transpose enc weights, convert Wout -> fp16, pack decoder weights
//       (Whh/Ww/Wih/Wc) to fp16 in PER-THREAD-CONTIGUOUS rows so the decode
//       kernel can hold its slice in registers for all 64 steps.
//   K2  encoder: enc_out [S,B,E], uh [S,B,A]  (f32, ws)
//   K3  decode: 64 WGs (one per batch lane), 1024 threads (16 waves = 4/SIMD),
//       T=64 sequential steps. enc_out/uh pinned in LDS. ALL GRU/attn weights
//       register-resident (<=20 half8 = 80 VGPR worst thread) => per-step
//       global traffic ~= one emb row. amdgpu_waves_per_eu(1,4): min=1 lifts
//       the VGPR cap to 512 (so ~100-VGPR demand fits without spilling),
//       max=4 matches the 149 KB-LDS-forced 1 WG/CU occupancy. Outer t-loop
//       unroll disabled to keep compile bounded (hedge vs round-3 container
//       failure) and I-cache small.
//   K4  logits pass1 (MFMA fp16): per-row-block online-softmax partials
//   K5  reduce partials -> L[row] = max + log(sumexp)
//   K6  logits pass2 (MFMA fp16): recompute tile, write x - L[row] (524 MB)
// ---------------------------------------------------------------------------

typedef _Float16 half8 __attribute__((ext_vector_type(8)));
typedef float floatx4 __attribute__((ext_vector_type(4)));

__device__ __forceinline__ float fast_tanh(float x) {
  float e = __expf(2.0f * x);
  return 1.0f - 2.0f / (e + 1.0f);   // saturates correctly when e -> inf / 0
}
__device__ __forceinline__ float fast_sigmoid(float x) {
  return 1.0f / (1.0f + __expf(-x));
}

// ---------------- prep kernels ----------------
__global__ void transpose_kernel(const float* __restrict__ src,
                                 float* __restrict__ dst, int R, int C) {
  int i = blockIdx.x * 256 + threadIdx.x;
  if (i < R * C) {
    int r = i / C, c = i - r * C;
    dst[c * R + r] = src[i];
  }
}

__global__ void cvt_f16_kernel(const float* __restrict__ src,
                               _Float16* __restrict__ dst, int n) {
  int i = blockIdx.x * 256 + threadIdx.x;
  if (i < n) dst[i] = (_Float16)src[i];
}

// Pack decoder weights fp32 -> fp16, per-decode-thread contiguous rows.
//  WaP [1024][64]: slot=tid, out=slot>>1 (0..511), part=slot&1, j=0..63
//      out<384 -> Whh[out][part*64+j]   (gh GEMV)
//      out>=384 -> Ww[out-384][part*64+j] (wq GEMV)
//  WiP [768][64]: part=slot>=384, g=slot-part*384 -> Wih[g][part*64+j]
//  WcP [1024][32]: sub=slot>>7, j=slot&127, i=0..31 -> Wc[j][sub*32+i]
__global__ void pack_weights_kernel(
    const float* __restrict__ Whh, const float* __restrict__ Ww,
    const float* __restrict__ Wih, const float* __restrict__ Wc,
    _Float16* __restrict__ WaP, _Float16* __restrict__ WiP,
    _Float16* __restrict__ WcP) {
  int i = blockIdx.x * 256 + threadIdx.x;
  if (i < 1024 * 64) {
    int slot = i >> 6, j = i & 63;
    int out = slot >> 1, part = slot & 1;
    float v = (out < 384) ? Whh[out * 128 + part * 64 + j]
                          : Ww[(out - 384) * 128 + part * 64 + j];
    WaP[i] = (_Float16)v;
    return;
  }
  int i2 = i - 1024 * 64;
  if (i2 < 768 * 64) {
    int slot = i2 >> 6, j = i2 & 63;
    int part = (slot >= 384) ? 1 : 0;
    int g = slot - part * 384;
    WiP[i2] = (_Float16)Wih[g * 128 + part * 64 + j];
    return;
  }
  int i3 = i2 - 768 * 64;
  if (i3 < 1024 * 32) {
    int slot = i3 >> 5, ii = i3 & 31;
    int sub = slot >> 7, j = slot & 127;
    WcP[i3] = (_Float16)Wc[j * 256 + sub * 32 + ii];
  }
}

// ---------------- encoder ----------------
// grid 8192 (= s*64+b), 128 threads. eo_ws/uh_ws layout: [(s*64+b)][128]
__global__ __launch_bounds__(128) void encoder_kernel(
    const float* __restrict__ emb, const float* __restrict__ WeT,
    const float* __restrict__ b_enc, const float* __restrict__ UwT,
    const float* __restrict__ U_b, const int* __restrict__ batch_x,
    float* __restrict__ eo_ws, float* __restrict__ uh_ws) {
  __shared__ float x[128];
  __shared__ float row[128];
  int idx = blockIdx.x;
  int tid = threadIdx.x;
  int id = batch_x[idx];
  x[tid] = emb[id * 128 + tid];
  __syncthreads();
  float acc = b_enc[tid];
#pragma unroll 4
  for (int d = 0; d < 128; ++d) acc += WeT[d * 128 + tid] * x[d];
  acc = fmaxf(acc, 0.0f);
  row[tid] = acc;
  eo_ws[idx * 128 + tid] = acc;
  __syncthreads();
  float a2 = U_b[tid];
#pragma unroll 4
  for (int e = 0; e < 128; ++e) a2 += UwT[e * 128 + tid] * row[e];
  uh_ws[idx * 128 + tid] = a2;
}

// ---------------- decoder ----------------
// 64 WGs (one per batch lane b), 1024 threads (16 waves), dyn LDS ~149 KB.
// Weights register-resident (fp16). Per step (10 barriers):
//   A    : all 1024 thr: out=tid>>1 (gh[0..383] | wq[0..127]), K-split2, 64 MAC
//   A-red: gh (384) | wq (128) | issue emb prefetch for t+1 (128)
//   B    : scores partials, 8-way A-split, 16 tanh/thread
//   B-red: wave0 reduces 8 partials + softmax (butterfly)
//   C    : ctx partials, 8-way s-split (eo in LDS)
//   C-red: ctx scale
//   D    : rnn partials, 8-way K-split over [py|ctx], 32 MAC
//   D-red: rnn (128) | write prefetched py_next (128)
//   E    : gi partials (768 thr, K-split2), 64 MAC
//   F    : gate fusion (gi reduce folded in) + h update + Hf store
__global__ __attribute__((amdgpu_flat_work_group_size(1024, 1024),
                          amdgpu_waves_per_eu(1, 4)))
void decode_kernel(
    const float* __restrict__ emb, const float* __restrict__ Wb,
    const float* __restrict__ vw, const float* __restrict__ vb,
    const float* __restrict__ Wcb, const float* __restrict__ bih,
    const float* __restrict__ bhh, const int* __restrict__ batch_y,
    const float* __restrict__ eo_ws, const float* __restrict__ uh_ws,
    const _Float16* __restrict__ WaP, const _Float16* __restrict__ WiP,
    const _Float16* __restrict__ WcP, _Float16* __restrict__ Hf) {
  extern __shared__ float sm[];
  float* eo  = sm;                 // 128*129 (pad stride 129: conflict-free)
  float* uhs = eo + 128 * 129;     // 128*129
  float* h   = uhs + 128 * 129;    // 128
  float* wq  = h + 128;            // 128
  float* sc  = wq + 128;           // 128
  float* ctx = sc + 128;           // 128
  float* py0 = ctx + 128;          // 128
  float* py1 = py0 + 128;          // 128
  float* rnn = py1 + 128;          // 128
  float* gh  = rnn + 128;          // 384 (reduced gh, incl bhh)
  float* gP  = gh + 384;           // 2*384 partials (gi in E)
  float* red = gP + 768;           // 1024 partials (A/B/C/D reuse)
  float* vws = red + 1024;         // 128 (v_w staged)
  float* bb  = vws + 128;          // 1024: Wb[128] bhh[384] Wcb[128] bih[384]
  float* scal = bb + 1024;         // [0]=1/softmax_sum, [1]=v_b

  const int tid = threadIdx.x;
  const int b = blockIdx.x;

  // ---- register-resident weights (fp16, per-thread contiguous rows) ----
  half8 wa[8], wi[8], wc[4];
  {
    const half8* pwa = (const half8*)(WaP + (size_t)tid * 64);
#pragma unroll
    for (int k = 0; k < 8; ++k) wa[k] = pwa[k];
    // threads >=768 load row 0 (valid memory, values unused)
    const half8* pwi =
        (const half8*)(WiP + (size_t)(tid < 768 ? tid : 0) * 64);
#pragma unroll
    for (int k = 0; k < 8; ++k) wi[k] = pwi[k];
    const half8* pwc = (const half8*)(WcP + (size_t)tid * 32);
#pragma unroll
    for (int k = 0; k < 4; ++k) wc[k] = pwc[k];
  }

  // ---- init: stage eo/uh tiles, v, biases ----
  for (int i = tid; i < 128 * 128; i += 1024) {
    int s = i >> 7, e = i & 127;
    eo[s * 129 + e]  = eo_ws[(s * 64 + b) * 128 + e];
    uhs[s * 129 + e] = uh_ws[(s * 64 + b) * 128 + e];
  }
  if (tid < 128) vws[tid] = vw[tid];
  if (tid < 128) bb[tid] = Wb[tid];
  else if (tid < 512) bb[tid] = bhh[tid - 128];
  else if (tid < 640) bb[tid] = Wcb[tid - 512];
  else bb[tid] = bih[tid - 640];
  if (tid == 0) scal[1] = vb[0];
  __syncthreads();
  // h0 = sum_s enc_out  (8-way split)
  {
    int e = tid & 127, sub = tid >> 7;
    float a0 = 0.f;
    for (int s = sub * 16; s < sub * 16 + 16; ++s) a0 += eo[s * 129 + e];
    red[sub * 128 + e] = a0;
  }
  __syncthreads();
  if (tid < 128) {
    float a = 0.f;
#pragma unroll
    for (int k = 0; k < 8; ++k) a += red[k * 128 + tid];
    h[tid] = a;
    py0[tid] = emb[(50000 - 1) * 128 + tid];   // BOS embedding
  }
  __syncthreads();

  float* pyCur = py0;
  float* pyNext = py1;
  float vPy = 0.f;

#pragma clang loop unroll(disable)
  for (int t = 0; t < 64; ++t) {
    // ---- phase A: gh[0..383] + wq[0..127] partials, weights in regs ----
    {
      const float* hh = h + ((tid & 1) << 6);
      float acc = 0.f;
#pragma unroll
      for (int k = 0; k < 8; ++k) {
#pragma unroll
        for (int l = 0; l < 8; ++l) acc += (float)wa[k][l] * hh[k * 8 + l];
      }
      red[tid] = acc;   // red[out*2 + part]
    }
    __syncthreads();
    // ---- A-reduce + prefetch issue ----
    if (tid < 384) {
      gh[tid] = red[2 * tid] + red[2 * tid + 1] + bb[128 + tid];
    } else if (tid < 512) {
      int a = tid - 384;
      wq[a] = red[2 * tid] + red[2 * tid + 1] + bb[a];
    } else if (tid < 640) {
      if (t < 63) {   // issue next step's prev_y embedding row load
        int pid = batch_y[t * 64 + b];
        vPy = emb[pid * 128 + (tid - 512)];
      }
    }
    __syncthreads();
    // ---- phase B: scores partials. s=tid&127, 16 tanh each ----
    {
      int s = tid & 127, sub = tid >> 7;
      const float* ur = uhs + s * 129 + sub * 16;
      const float* wr = wq + sub * 16;
      const float* vr = vws + sub * 16;
      float acc = 0.f;
#pragma unroll
      for (int a = 0; a < 16; ++a) acc += vr[a] * fast_tanh(wr[a] + ur[a]);
      red[sub * 128 + s] = acc;
    }
    __syncthreads();
    // ---- B-reduce + softmax (wave 0) ----
    if (tid < 64) {
      float s0 = scal[1], s1 = scal[1];
#pragma unroll
      for (int k = 0; k < 8; ++k) {
        s0 += red[k * 128 + tid];
        s1 += red[k * 128 + tid + 64];
      }
      float m = fmaxf(s0, s1);
      for (int o = 32; o >= 1; o >>= 1) m = fmaxf(m, __shfl_xor(m, o, 64));
      float e0_ = __expf(s0 - m);
      float e1_ = __expf(s1 - m);
      sc[tid] = e0_; sc[tid + 64] = e1_;
      float ss = e0_ + e1_;
      for (int o = 32; o >= 1; o >>= 1) ss += __shfl_xor(ss, o, 64);
      if (tid == 0) scal[0] = 1.0f / ss;
    }
    __syncthreads();
    // ---- phase C: ctx partials, 8-way s-split ----
    {
      int e = tid & 127, sub = tid >> 7;
      float a0 = 0.f, a1 = 0.f;
      for (int s = sub * 16; s < sub * 16 + 16; s += 2) {
        a0 += sc[s] * eo[s * 129 + e];
        a1 += sc[s + 1] * eo[(s + 1) * 129 + e];
      }
      red[sub * 128 + e] = a0 + a1;
    }
    __syncthreads();
    if (tid < 128) {
      float a = 0.f;
#pragma unroll
      for (int k = 0; k < 8; ++k) a += red[k * 128 + tid];
      ctx[tid] = a * scal[0];
    }
    __syncthreads();
    // ---- phase D: rnn partials, 8-way K-split over [py|ctx], regs ----
    {
      int sub = tid >> 7, j = tid & 127;
      const float* src = (sub < 4) ? (pyCur + sub * 32) : (ctx + (sub - 4) * 32);
      float acc = 0.f;
#pragma unroll
      for (int k = 0; k < 4; ++k) {
#pragma unroll
        for (int l = 0; l < 8; ++l) acc += (float)wc[k][l] * src[k * 8 + l];
      }
      red[sub * 128 + j] = acc;
    }
    __syncthreads();
    // ---- D-reduce + prefetch write ----
    if (tid < 128) {
      float a = 0.f;
#pragma unroll
      for (int k = 0; k < 8; ++k) a += red[k * 128 + tid];
      rnn[tid] = a + bb[512 + tid];
    } else if (tid >= 512 && tid < 640) {
      if (t < 63) pyNext[tid - 512] = vPy;
    }
    __syncthreads();
    // ---- phase E: gi partials (768 thr, K-split2), regs ----
    if (tid < 768) {
      int part = (tid >= 384) ? 1 : 0;
      int g = tid - part * 384;
      const float* rr = rnn + (part << 6);
      float acc = 0.f;
#pragma unroll
      for (int k = 0; k < 8; ++k) {
#pragma unroll
        for (int l = 0; l < 8; ++l) acc += (float)wi[k][l] * rr[k * 8 + l];
      }
      gP[part * 384 + g] = acc;
    }
    __syncthreads();
    // ---- phase F: gate fusion (gi reduce folded in) + h update ----
    if (tid < 128) {
      float ir = gP[tid] + gP[384 + tid] + bb[640 + tid];
      float iz = gP[128 + tid] + gP[384 + 128 + tid] + bb[640 + 128 + tid];
      float in_ = gP[256 + tid] + gP[384 + 256 + tid] + bb[640 + 256 + tid];
      float r = fast_sigmoid(ir + gh[tid]);
      float z = fast_sigmoid(iz + gh[128 + tid]);
      float ng = fast_tanh(in_ + r * gh[256 + tid]);
      float hn = (1.f - z) * ng + z * h[tid];
      h[tid] = hn;
      Hf[(t * 64 + b) * 128 + tid] = (_Float16)hn;
    }
    __syncthreads();
    float* tmp = pyCur; pyCur = pyNext; pyNext = tmp;
  }
}

// ---------------- logits GEMM (fp16 MFMA) ----------------
// grid (250, 32), 256 threads; 128x128 C-tile per WG; K=128.
// LDS: A-tile + B-tile, fp16, row stride 136 (2-way conflicts only).
// PASS 1: per-row (max, sumexp) partials over this 128-col block.
// PASS 2: out[row][col] = x - L[row].
template <int PASS>
__global__ __launch_bounds__(256) void logits_kernel(
    const _Float16* __restrict__ Ah,   // [4096][128]
    const _Float16* __restrict__ Bh,   // [32000][128] (Wout rows, K-major)
    const float* __restrict__ bout, const float* __restrict__ Lrow,
    float* __restrict__ pmax, float* __restrict__ psum,
    float* __restrict__ out) {
  extern __shared__ char smem_raw[];
  _Float16* At = (_Float16*)smem_raw;                 // 128*136
  _Float16* Bt = (_Float16*)(smem_raw + 128 * 136 * 2);

  const int nb = blockIdx.x;   // 0..249
  const int mb = blockIdx.y;   // 0..31
  const int tid = threadIdx.x;
  const int lane = tid & 63;
  const int wid = tid >> 6;
  const int m0 = mb * 128, n0 = nb * 128;

  const uint4* Ag = (const uint4*)(Ah + (size_t)m0 * 128);
  const uint4* Bg = (const uint4*)(Bh + (size_t)n0 * 128);
  for (int i = tid; i < 2048; i += 256) {
    int r = i >> 4, c = i & 15;
    *(uint4*)(At + r * 136 + c * 8) = Ag[r * 16 + c];
    *(uint4*)(Bt + r * 136 + c * 8) = Bg[r * 16 + c];
  }
  __syncthreads();

  const int wm = wid >> 1, wn = wid & 1;
  const int lr = lane & 15;
  const int quad = lane >> 4;

  floatx4 acc[4][4];
  const floatx4 z4 = {0.f, 0.f, 0.f, 0.f};
  for (int i = 0; i < 4; ++i)
    for (int j = 0; j < 4; ++j) acc[i][j] = z4;

  for (int kk = 0; kk < 4; ++kk) {
    int kof = kk * 32 + quad * 8;
    half8 af[4], bfr[4];
#pragma unroll
    for (int ms = 0; ms < 4; ++ms)
      af[ms] = *(const half8*)(At + (wm * 64 + ms * 16 + lr) * 136 + kof);
#pragma unroll
    for (int ns = 0; ns < 4; ++ns)
      bfr[ns] = *(const half8*)(Bt + (wn * 64 + ns * 16 + lr) * 136 + kof);
#pragma unroll
    for (int ms = 0; ms < 4; ++ms)
#pragma unroll
      for (int ns = 0; ns < 4; ++ns)
        acc[ms][ns] = __builtin_amdgcn_mfma_f32_16x16x32_f16(
            af[ms], bfr[ns], acc[ms][ns], 0, 0, 0);
  }

  float bcol[4];
#pragma unroll
  for (int ns = 0; ns < 4; ++ns)
    bcol[ns] = bout[n0 + wn * 64 + ns * 16 + lr];

  if (PASS == 1) {
    __syncthreads();   // done with tiles; reuse LDS for reductions
    float* red_m = (float*)smem_raw;   // [2][128]
    float* red_s = red_m + 256;        // [2][128]
#pragma unroll
    for (int ms = 0; ms < 4; ++ms) {
#pragma unroll
      for (int r = 0; r < 4; ++r) {
        float v0 = acc[ms][0][r] + bcol[0];
        float v1 = acc[ms][1][r] + bcol[1];
        float v2 = acc[ms][2][r] + bcol[2];
        float v3 = acc[ms][3][r] + bcol[3];
        float vmax = fmaxf(fmaxf(v0, v1), fmaxf(v2, v3));
        for (int o = 1; o < 16; o <<= 1)
          vmax = fmaxf(vmax, __shfl_xor(vmax, o, 16));
        float s = __expf(v0 - vmax) + __expf(v1 - vmax) +
                  __expf(v2 - vmax) + __expf(v3 - vmax);
        for (int o = 1; o < 16; o <<= 1) s += __shfl_xor(s, o, 16);
        if (lr == 0) {
          int row = wm * 64 + ms * 16 + quad * 4 + r;
          red_m[wn * 128 + row] = vmax;
          red_s[wn * 128 + row] = s;
        }
      }
    }
    __syncthreads();
    if (tid < 128) {
      float ma = red_m[tid], mb2 = red_m[128 + tid];
      float M = fmaxf(ma, mb2);
      float S = red_s[tid] * __expf(ma - M) + red_s[128 + tid] * __expf(mb2 - M);
      pmax[(size_t)(m0 + tid) * 250 + nb] = M;
      psum[(size_t)(m0 + tid) * 250 + nb] = S;
    }
  } else {
#pragma unroll
    for (int ms = 0; ms < 4; ++ms) {
#pragma unroll
      for (int r = 0; r < 4; ++r) {
        int grow = m0 + wm * 64 + ms * 16 + quad * 4 + r;
        float L = Lrow[grow];
        float* orow = out + (size_t)grow * 32000 + n0 + wn * 64 + lr;
#pragma unroll
        for (int ns = 0; ns < 4; ++ns)
          orow[ns * 16] = acc[ms][ns][r] + bcol[ns] - L;
      }
    }
  }
}

__global__ void reduce_l_kernel(const float* __restrict__ pmax,
                                const float* __restrict__ psum,
                                float* __restrict__ Lrow) {
  int row = blockIdx.x * 256 + threadIdx.x;
  if (row >= 4096) return;
  const float* pm = pmax + (size_t)row * 250;
  const float* ps = psum + (size_t)row * 250;
  float M = -1e30f;
  for (int i = 0; i < 250; ++i) M = fmaxf(M, pm[i]);
  float S = 0.f;
  for (int i = 0; i < 250; ++i) S += ps[i] * __expf(pm[i] - M);
  Lrow[row] = M + logf(S);
}

// ---------------------------------------------------------------------------
extern "C" void kernel_launch(void* const* d_in, const int* in_sizes, int n_in,
                              void* d_out, int out_size, void* d_ws,
                              size_t ws_size, hipStream_t stream) {
  const float* emb   = (const float*)d_in[0];
  const float* W_enc = (const float*)d_in[1];
  const float* b_enc = (const float*)d_in[2];
  const float* U_w   = (const float*)d_in[3];
  const float* U_b   = (const float*)d_in[4];
  const float* Ww    = (const float*)d_in[5];
  const float* Wb    = (const float*)d_in[6];
  const float* v_w   = (const float*)d_in[7];
  const float* v_b   = (const float*)d_in[8];
  const float* Wc_w  = (const float*)d_in[9];
  const float* Wc_b  = (const float*)d_in[10];
  const float* Wih   = (const float*)d_in[11];
  const float* bih   = (const float*)d_in[12];
  const float* Whh   = (const float*)d_in[13];
  const float* bhh   = (const float*)d_in[14];
  const float* Wout  = (const float*)d_in[15];
  const float* bout  = (const float*)d_in[16];
  const int* batch_x = (const int*)d_in[17];
  const int* batch_y = (const int*)d_in[18];
  float* out = (float*)d_out;

  char* w = (char*)d_ws;
  size_t off = 0;
  auto alloc = [&](size_t bytes) {
    void* p = w + off;
    off += (bytes + 255) & ~(size_t)255;
    return p;
  };
  float* eo_ws = (float*)alloc(128 * 64 * 128 * 4);
  float* uh_ws = (float*)alloc(128 * 64 * 128 * 4);
  float* WeT   = (float*)alloc(128 * 128 * 4);
  float* UwT   = (float*)alloc(128 * 128 * 4);
  _Float16* WaP = (_Float16*)alloc(1024 * 64 * 2);
  _Float16* WiP = (_Float16*)alloc(768 * 64 * 2);
  _Float16* WcP = (_Float16*)alloc(1024 * 32 * 2);
  _Float16* Hf  = (_Float16*)alloc(4096 * 128 * 2);
  _Float16* WoH = (_Float16*)alloc((size_t)32000 * 128 * 2);
  float* pmax = (float*)alloc((size_t)4096 * 250 * 4);
  float* psum = (float*)alloc((size_t)4096 * 250 * 4);
  float* Lrow = (float*)alloc(4096 * 4);
  (void)ws_size; (void)in_sizes; (void)n_in; (void)out_size;

  // opt-in >64KB dynamic LDS (idempotent; not a stream op)
  const int DEC_SH = (2 * 128 * 129 + 9 * 128 + 384 + 768 + 1024 + 1024 + 4) * 4;
  const int P3_SH = 2 * 128 * 136 * 2;                                  // 69632
  hipFuncSetAttribute((const void*)decode_kernel,
                      hipFuncAttributeMaxDynamicSharedMemorySize, DEC_SH);
  hipFuncSetAttribute((const void*)(logits_kernel<1>),
                      hipFuncAttributeMaxDynamicSharedMemorySize, P3_SH);
  hipFuncSetAttribute((const void*)(logits_kernel<2>),
                      hipFuncAttributeMaxDynamicSharedMemorySize, P3_SH);

  // prep: transposes + fp16 convert + decoder weight pack
  transpose_kernel<<<(128 * 128 + 255) / 256, 256, 0, stream>>>(W_enc, WeT, 128, 128);
  transpose_kernel<<<(128 * 128 + 255) / 256, 256, 0, stream>>>(U_w, UwT, 128, 128);
  cvt_f16_kernel<<<(32000 * 128 + 255) / 256, 256, 0, stream>>>(Wout, WoH, 32000 * 128);
  pack_weights_kernel<<<(1024 * 64 + 768 * 64 + 1024 * 32) / 256, 256, 0,
                        stream>>>(Whh, Ww, Wih, Wc_w, WaP, WiP, WcP);

  encoder_kernel<<<128 * 64, 128, 0, stream>>>(emb, WeT, b_enc, UwT, U_b,
                                               batch_x, eo_ws, uh_ws);

  decode_kernel<<<64, 1024, DEC_SH, stream>>>(emb, Wb, v_w, v_b, Wc_b, bih,
                                              bhh, batch_y, eo_ws, uh_ws,
                                              WaP, WiP, WcP, Hf);

  dim3 g3(250, 32);
  logits_kernel<1><<<g3, 256, P3_SH, stream>>>(Hf, WoH, bout, nullptr, pmax,
                                               psum, nullptr);
  reduce_l_kernel<<<16, 256, 0, stream>>>(pmax, psum, Lrow);
  logits_kernel<2><<<g3, 256, P3_SH, stream>>>(Hf, WoH, bout, Lrow, nullptr,
                                               nullptr, out);
}